// Round 1
// baseline (196.943 us; speedup 1.0000x reference)
//
#include <hip/hip_runtime.h>

// Problem shape (fixed by setup_inputs): B=64, C=1024, H*W=1024, M=768.
#define NB 64
#define NC 1024
#define HW 1024
#define HW4 256          // HW / 4 (float4 granularity)
#define CCH 8            // split-K channel chunks
#define CPC (NC / CCH)   // 128 channels per chunk

// Kernel A: partial GEMV. logit_partial[cchunk][b][hw] = sum over 128 channels
// of fm[b,c,hw] * w[c]. Fully coalesced float4 reads (1 KB/wave/row).
__global__ void adl_partial_gemv(const float* __restrict__ fm,
                                 const float* __restrict__ w,
                                 float* __restrict__ partial) {
    const int cchunk = blockIdx.x;
    const int b      = blockIdx.y;
    const int t      = threadIdx.x;          // 0..255 -> hw 4t..4t+3
    const float4* fm4 = (const float4*)fm;
    float4 acc = make_float4(0.f, 0.f, 0.f, 0.f);
    const int cbase = cchunk * CPC;
    #pragma unroll 4
    for (int ci = 0; ci < CPC; ++ci) {
        const int c = cbase + ci;
        const float4 v = fm4[((size_t)(b * NC + c)) * HW4 + t];
        const float wv = w[c];
        acc.x += v.x * wv;
        acc.y += v.y * wv;
        acc.z += v.z * wv;
        acc.w += v.w * wv;
    }
    ((float4*)partial)[((size_t)(cchunk * NB + b)) * HW4 + t] = acc;
}

// Kernel B: reduce partials, sigmoid, write attn output, compute exact top-M
// drop mask via per-element descending rank (value desc, index asc tiebreak —
// matches jax.lax.top_k selection). One block per batch, 1024 threads.
__global__ void adl_topk_mask(const float* __restrict__ partial,
                              const float* __restrict__ conv_b,
                              const int* __restrict__ Mptr,
                              float* __restrict__ attn_out,
                              float* __restrict__ mask) {
    __shared__ float a_sh[HW];
    const int b = blockIdx.x;
    const int t = threadIdx.x;               // 0..1023, one spatial location
    float s = conv_b[0];
    #pragma unroll
    for (int k = 0; k < CCH; ++k)
        s += partial[((size_t)(k * NB + b)) * HW + t];
    const float a = 1.0f / (1.0f + expf(-s));
    a_sh[t] = a;
    attn_out[(size_t)b * HW + t] = a;
    __syncthreads();
    const int M = *Mptr;
    int r = 0;
    #pragma unroll 8
    for (int j = 0; j < HW; ++j) {
        const float aj = a_sh[j];            // broadcast read, no bank conflict
        r += (aj > a) || (aj == a && j < t);
    }
    mask[(size_t)b * HW + t] = (r < M) ? 0.0f : 1.0f;
}

// Kernel C: dropped = fm * mask (mask broadcast over channels). Grid-stride,
// float4 both sides; mask (256 KB) stays L2/L3 resident.
__global__ void adl_apply(const float* __restrict__ fm,
                          const float* __restrict__ mask,
                          float* __restrict__ out) {
    const float4* fm4   = (const float4*)fm;
    const float4* mask4 = (const float4*)mask;
    float4* out4        = (float4*)out;
    const size_t total4 = (size_t)NB * NC * HW4;   // 16,777,216
    const size_t stride = (size_t)gridDim.x * blockDim.x;
    for (size_t i = (size_t)blockIdx.x * blockDim.x + threadIdx.x;
         i < total4; i += stride) {
        const int hw4 = (int)(i & (HW4 - 1));
        const int bc  = (int)(i >> 8);
        const int b   = bc >> 10;                  // bc / NC
        const float4 m = mask4[b * HW4 + hw4];
        const float4 v = fm4[i];
        float4 o;
        o.x = v.x * m.x;
        o.y = v.y * m.y;
        o.z = v.z * m.z;
        o.w = v.w * m.w;
        out4[i] = o;
    }
}

extern "C" void kernel_launch(void* const* d_in, const int* in_sizes, int n_in,
                              void* d_out, int out_size, void* d_ws, size_t ws_size,
                              hipStream_t stream) {
    const float* fm   = (const float*)d_in[0];   // [64,1024,32,32] f32
    const float* w    = (const float*)d_in[1];   // [1024] f32
    const float* bias = (const float*)d_in[2];   // [1] f32
    const int*   Mptr = (const int*)d_in[3];     // scalar int (768)

    float* out      = (float*)d_out;                       // dropped [B,C,H,W]
    float* attn_out = out + (size_t)NB * NC * HW;          // attn [B,1,H,W]

    float* partial = (float*)d_ws;                         // [CCH][B][HW] f32
    float* mask    = partial + (size_t)CCH * NB * HW;      // [B][HW] f32

    adl_partial_gemv<<<dim3(CCH, NB), 256, 0, stream>>>(fm, w, partial);
    adl_topk_mask<<<NB, HW, 0, stream>>>(partial, bias, Mptr, attn_out, mask);
    adl_apply<<<2048, 256, 0, stream>>>(fm, mask, out);
}

// Round 2
// 179.020 us; speedup vs baseline: 1.1001x; 1.1001x over previous
//
#include <hip/hip_runtime.h>

typedef float f32x4 __attribute__((ext_vector_type(4)));

// Problem shape (fixed by setup_inputs): B=64, C=1024, H*W=1024, M=768.
#define NB 64
#define NC 1024
#define HW 1024
#define HW4 256          // HW / 4

// Kernel A: split-K partial GEMV. partial[cchunk][b][hw] = sum over CPC
// channels of fm[b,c,hw] * w[c]. Coalesced 16 B/lane reads.
template<int CPC>
__global__ void adl_partial_gemv(const float* __restrict__ fm,
                                 const float* __restrict__ w,
                                 float* __restrict__ partial) {
    const int cchunk = blockIdx.x;
    const int b      = blockIdx.y;
    const int t      = threadIdx.x;          // 0..255 -> hw 4t..4t+3
    const f32x4* fm4 = (const f32x4*)fm;
    f32x4 acc = {0.f, 0.f, 0.f, 0.f};
    const int cbase = cchunk * CPC;
    #pragma unroll 8
    for (int ci = 0; ci < CPC; ++ci) {
        const int c = cbase + ci;
        const f32x4 v = fm4[((size_t)(b * NC + c)) * HW4 + t];
        acc += v * w[c];
    }
    ((f32x4*)partial)[((size_t)(cchunk * NB + b)) * HW4 + t] = acc;
}

// Kernel B: reduce partials -> logit, sigmoid -> attn output, exact top-M
// drop mask via per-element descending rank with index tie-break (matches
// lax.top_k). Rank on the LOGIT (sigmoid is strictly monotone) so mask
// selection is independent of exp() rounding. Grid: (4 slices, 64 batches),
// 256 threads; every block builds the full 1024-entry logit row in LDS.
__global__ void adl_topk_mask(const float* __restrict__ partial,
                              const float* __restrict__ conv_b,
                              const int* __restrict__ Mptr,
                              int ncch,
                              float* __restrict__ attn_out,
                              float* __restrict__ mask) {
    __shared__ f32x4 s_sh4[HW4];
    float* s_sh = (float*)s_sh4;
    const int slice = blockIdx.x;            // 0..3
    const int b     = blockIdx.y;
    const int tid   = threadIdx.x;           // 0..255
    const float bias = conv_b[0];
    #pragma unroll
    for (int q = 0; q < 4; ++q) {
        const int t = q * 256 + tid;
        float s = bias;
        for (int k = 0; k < ncch; ++k)
            s += partial[((size_t)(k * NB + b)) * HW + t];
        s_sh[t] = s;
    }
    __syncthreads();
    const int t = slice * 256 + tid;         // this thread's element
    const float sv = s_sh[t];
    const int M = *Mptr;
    int r = 0;
    #pragma unroll 4
    for (int j4 = 0; j4 < HW4; ++j4) {
        const f32x4 v = s_sh4[j4];           // broadcast LDS read
        const int j = j4 * 4;
        r += (v.x > sv) || (v.x == sv && (j + 0) < t);
        r += (v.y > sv) || (v.y == sv && (j + 1) < t);
        r += (v.z > sv) || (v.z == sv && (j + 2) < t);
        r += (v.w > sv) || (v.w == sv && (j + 3) < t);
    }
    attn_out[(size_t)b * HW + t] = 1.0f / (1.0f + expf(-sv));
    mask[(size_t)b * HW + t] = (r < M) ? 0.0f : 1.0f;
}

// Kernel C: dropped = fm * mask (mask broadcast over channels). Nontemporal
// stores keep the 256 MiB out-stream from evicting fm in L3, so the second
// fm read hits Infinity Cache.
__global__ void adl_apply(const float* __restrict__ fm,
                          const float* __restrict__ mask,
                          float* __restrict__ out) {
    const f32x4* fm4   = (const f32x4*)fm;
    const f32x4* mask4 = (const f32x4*)mask;
    f32x4* out4        = (f32x4*)out;
    const size_t total4 = (size_t)NB * NC * HW4;   // 16,777,216
    const size_t stride = (size_t)gridDim.x * blockDim.x;
    for (size_t i = (size_t)blockIdx.x * blockDim.x + threadIdx.x;
         i < total4; i += stride) {
        const int hw4 = (int)(i & (HW4 - 1));
        const int b   = (int)(i >> 18);            // i / (NC*HW4), 2^18
        const f32x4 m = mask4[b * HW4 + hw4];
        const f32x4 v = fm4[i];
        __builtin_nontemporal_store(v * m, &out4[i]);
    }
}

extern "C" void kernel_launch(void* const* d_in, const int* in_sizes, int n_in,
                              void* d_out, int out_size, void* d_ws, size_t ws_size,
                              hipStream_t stream) {
    const float* fm   = (const float*)d_in[0];   // [64,1024,32,32] f32
    const float* w    = (const float*)d_in[1];   // [1024] f32
    const float* bias = (const float*)d_in[2];   // [1] f32
    const int*   Mptr = (const int*)d_in[3];     // scalar int (768)

    float* out      = (float*)d_out;                       // dropped [B,C,H,W]
    float* attn_out = out + (size_t)NB * NC * HW;          // attn [B,1,H,W]

    // Workspace: partial [ncch][B][HW] f32 + mask [B][HW] f32.
    const size_t need16 = ((size_t)16 * NB * HW + (size_t)NB * HW) * sizeof(float);
    const int ncch = (ws_size >= need16) ? 16 : 8;
    float* partial = (float*)d_ws;
    float* mask    = partial + (size_t)ncch * NB * HW;

    if (ncch == 16)
        adl_partial_gemv<NC / 16><<<dim3(16, NB), 256, 0, stream>>>(fm, w, partial);
    else
        adl_partial_gemv<NC / 8><<<dim3(8, NB), 256, 0, stream>>>(fm, w, partial);
    adl_topk_mask<<<dim3(4, NB), 256, 0, stream>>>(partial, bias, Mptr, ncch, attn_out, mask);
    adl_apply<<<2048, 256, 0, stream>>>(fm, mask, out);
}